// Round 12
// baseline (229.785 us; speedup 1.0000x reference)
//
#include <hip/hip_runtime.h>

#define NN 100000
#define NE 800000

typedef __attribute__((ext_vector_type(4))) float f32x4;
typedef __attribute__((ext_vector_type(4))) int   i32x4;
typedef __attribute__((ext_vector_type(8))) unsigned short u16x8;

__device__ __forceinline__ unsigned short f2bf(float f) {
  unsigned u = __float_as_uint(f);
  return (unsigned short)((u + 0x7FFFu + ((u >> 16) & 1u)) >> 16);
}
__device__ __forceinline__ float bf2f(unsigned short b) {
  return __uint_as_float(((unsigned)b) << 16);
}

// ---------------- fused prologue: degree (8 XCD-local replicas) + x cast + W cast ------
// c = blockIdx&7 ~ XCD id (round-robin dispatch): atomics stay in the XCD's own L2,
// no cross-XCD line ping-pong. Correctness independent of the actual block->XCD map.
#define NBDEG 3125                   // 800000 / 256
#define NXV   (NN * 128 / 4)         // 3200000 float4 chunks
#define NBX   12500                  // NXV / 256
#define NBW   512                    // 131072 / 256
__global__ __launch_bounds__(256) void prep_k(
    const float* __restrict__ x,
    const float* __restrict__ Wa, const float* __restrict__ Wbm,
    const float* __restrict__ Wc, const float* __restrict__ Wd,
    const int* __restrict__ dst,
    unsigned short* __restrict__ xb, unsigned short* __restrict__ Wbo,
    int* __restrict__ deg8, int* __restrict__ rord) {
  int bid = blockIdx.x, t = threadIdx.x;
  if (bid < NBDEG) {
    int e = bid * 256 + t;
    int c = bid & 7;
    int o = atomicAdd(&deg8[c * NN + dst[e]], 1);
    __builtin_nontemporal_store((o << 3) | c, &rord[e]);
  } else if (bid < NBDEG + NBX) {
    int i = (bid - NBDEG) * 256 + t;
    float4 v = *reinterpret_cast<const float4*>(x + (size_t)i * 4);
    ushort4 o;
    o.x = f2bf(v.x); o.y = f2bf(v.y); o.z = f2bf(v.z); o.w = f2bf(v.w);
    *reinterpret_cast<ushort4*>(xb + (size_t)i * 4) = o;
  } else {
    int k = (bid - NBDEG - NBX) * 256 + t;
    int seg = k >> 15, off = k & 32767;
    const float* s = (seg < 2) ? (seg == 0 ? Wa : Wbm) : (seg == 2 ? Wc : Wd);
    Wbo[k] = f2bf(s[off]);
  }
}

// ---------------- CSR scans ----------------
// scan1: sum 8 replicas -> degt/inv, block-level exclusive scan (partial) -> offs, bsum
__global__ __launch_bounds__(256) void scan1_k(const int* __restrict__ deg8,
    int* __restrict__ degt, int* __restrict__ offs, int* __restrict__ bsum,
    float* __restrict__ inv) {
  __shared__ int s[256];
  int t = threadIdx.x;
  int base = blockIdx.x * 1024 + t * 4;
  int v[4], tsum = 0;
#pragma unroll
  for (int k = 0; k < 4; ++k) {
    int i = base + k;
    int d = 0;
    if (i < NN) {
#pragma unroll
      for (int c = 0; c < 8; ++c) d += deg8[c * NN + i];
      degt[i] = d;
      inv[i] = 1.0f / fmaxf((float)d, 1.0f);
    }
    v[k] = d;
    tsum += d;
  }
  s[t] = tsum; __syncthreads();
  int val = tsum;
#pragma unroll
  for (int off = 1; off < 256; off <<= 1) {
    int x = (t >= off) ? s[t - off] : 0;
    __syncthreads();
    val += x; s[t] = val;
    __syncthreads();
  }
  int excl = val - tsum;
  if (t == 255) bsum[blockIdx.x] = val;
  int run = excl;
#pragma unroll
  for (int k = 0; k < 4; ++k) { int i = base + k; if (i < NN) offs[i] = run; run += v[k]; }
}

__global__ __launch_bounds__(256) void scan2_k(int* __restrict__ bsum, int nb) {
  __shared__ int s[256];
  int t = threadIdx.x;
  int v = (t < nb) ? bsum[t] : 0;
  s[t] = v; __syncthreads();
  int val = v;
#pragma unroll
  for (int off = 1; off < 256; off <<= 1) {
    int x = (t >= off) ? s[t - off] : 0;
    __syncthreads();
    val += x; s[t] = val;
    __syncthreads();
  }
  if (t < nb) bsum[t] = val - v;
}

// fin: offs2[i] = finalized base; xcdoff[c][i] = base + sum_{c'<c} deg8[c'][i]
#define NBFIN 98                     // ceil(NN/1024)
__global__ __launch_bounds__(256) void fin_k(
    const int* __restrict__ offs, const int* __restrict__ bsum,
    const int* __restrict__ deg8,
    int* __restrict__ offs2, int* __restrict__ xcdoff) {
  int t = threadIdx.x;
  int add = bsum[blockIdx.x];
  int base_i = blockIdx.x * 1024 + t * 4;
#pragma unroll
  for (int k = 0; k < 4; ++k) {
    int i = base_i + k;
    if (i < NN) {
      int run = offs[i] + add;
      offs2[i] = run;
#pragma unroll
      for (int c = 0; c < 8; ++c) {
        xcdoff[c * NN + i] = run;
        run += deg8[c * NN + i];
      }
    }
  }
}

// atomic-free fill via per-replica bases
__global__ void fill_k(const int* __restrict__ src, const int* __restrict__ dst,
    const int* __restrict__ xcdoff, const int* __restrict__ rord,
    int* __restrict__ eidx) {
  int e = blockIdx.x * 256 + threadIdx.x;
  if (e < NE) {
    int rv = rord[e];
    int p = xcdoff[(rv & 7) * NN + dst[e]] + (rv >> 3);
    __builtin_nontemporal_store(src[e], &eidx[p]);
  }
}

// ---------------- gather (bf16 table, fp32 accum, deep ILP, grid-stride) ----------------
// 16 lanes/node, 16B (8 bf16) per lane; unroll x8 + x4 + scalar tails.
// GMODE 0: outb(bf16)[node] = bf16(inv*sum(feat[nbr]))
// GMODE 2: outf(f32)[node]  = bf2f(selfb[node]) + inv*sum(feat[nbr])  (nt store)
template<int GMODE>
__global__ __launch_bounds__(256) void gather_k(const unsigned short* __restrict__ feat,
    const int* __restrict__ offs, const int* __restrict__ deg,
    const float* __restrict__ inv, const int* __restrict__ eidx,
    const unsigned short* __restrict__ selfb,
    unsigned short* __restrict__ outb, float* __restrict__ outf) {
  const int l = threadIdx.x & 15;
  for (int nb = blockIdx.x * 16; nb < NN; nb += gridDim.x * 16) {
    int node = nb + (threadIdx.x >> 4);
    if (node >= NN) continue;
    int st = offs[node], n = deg[node];
    float a[8];
#pragma unroll
    for (int k = 0; k < 8; ++k) a[k] = 0.f;

    int j = 0;
    for (; j + 8 <= n; j += 8) {
      int si[8];
#pragma unroll
      for (int q = 0; q < 8; ++q) si[q] = eidx[st + j + q];
      u16x8 r[8];
#pragma unroll
      for (int q = 0; q < 8; ++q)
        r[q] = *reinterpret_cast<const u16x8*>(feat + (size_t)si[q] * 128 + l * 8);
#pragma unroll
      for (int q = 0; q < 8; ++q)
#pragma unroll
        for (int k = 0; k < 8; ++k) a[k] += bf2f(r[q][k]);
    }
    for (; j + 4 <= n; j += 4) {
      int si[4];
#pragma unroll
      for (int q = 0; q < 4; ++q) si[q] = eidx[st + j + q];
      u16x8 r[4];
#pragma unroll
      for (int q = 0; q < 4; ++q)
        r[q] = *reinterpret_cast<const u16x8*>(feat + (size_t)si[q] * 128 + l * 8);
#pragma unroll
      for (int q = 0; q < 4; ++q)
#pragma unroll
        for (int k = 0; k < 8; ++k) a[k] += bf2f(r[q][k]);
    }
    for (; j < n; ++j) {
      int s = eidx[st + j];
      u16x8 r = *reinterpret_cast<const u16x8*>(feat + (size_t)s * 128 + l * 8);
#pragma unroll
      for (int k = 0; k < 8; ++k) a[k] += bf2f(r[k]);
    }

    float sc = inv[node];
    if (GMODE == 2) {
      u16x8 sb = *reinterpret_cast<const u16x8*>(selfb + (size_t)node * 128 + l * 8);
      f32x4 o0, o1;
      o0[0] = bf2f(sb[0]) + sc * a[0]; o0[1] = bf2f(sb[1]) + sc * a[1];
      o0[2] = bf2f(sb[2]) + sc * a[2]; o0[3] = bf2f(sb[3]) + sc * a[3];
      o1[0] = bf2f(sb[4]) + sc * a[4]; o1[1] = bf2f(sb[5]) + sc * a[5];
      o1[2] = bf2f(sb[6]) + sc * a[6]; o1[3] = bf2f(sb[7]) + sc * a[7];
      float* po = outf + (size_t)node * 128 + l * 8;
      __builtin_nontemporal_store(o0, reinterpret_cast<f32x4*>(po));
      __builtin_nontemporal_store(o1, reinterpret_cast<f32x4*>(po + 4));
    } else {
      u16x8 o;
#pragma unroll
      for (int k = 0; k < 8; ++k) o[k] = f2bf(sc * a[k]);
      *reinterpret_cast<u16x8*>(outb + (size_t)node * 128 + l * 8) = o;
    }
  }
}

// ---------------- persistent bf16 MFMA GEMM (64 rows x 256 cols / panel) --------
// Grid = 512 persistent blocks (2/CU, 64KB LDS dbuf). B fragments preloaded once.
// Panel loop: stage(next)->vmcnt(8) counted->raw barrier->MFMA+stores->raw barrier.
// MODE 0 (layer 1): A=[A1|A2] k-concat; B k-concat; out = bf16 relu(C+bias) -> outb [NN,256].
// MODE 1 (layer 2): A=A1 [M,256]; B out-concat; waves 0-1 -> outb = bf16(h@W2l) [NN,128];
//   waves 2-3 -> outb2 = bf16(h@W2r + bias) [NN,128].
template<int MODE>
__global__ __launch_bounds__(256, 2) void mgemm_k(
    const unsigned short* __restrict__ A1, const unsigned short* __restrict__ A2,
    const unsigned short* __restrict__ Wbase, const float* __restrict__ bias,
    unsigned short* __restrict__ outb, unsigned short* __restrict__ outb2) {
  __shared__ unsigned short As[2][64 * 256];   // 2 x 32 KB, row stride 512 B
  const int t = threadIdx.x;
  const int wave = t >> 6, lane = t & 63;
  const int lhi = lane >> 4, llo = lane & 15;

  // ---- B fragments + bias, loaded once (weights are L2-resident) ----
  i32x4 bfrag[8][4];
  float bv[4];
#pragma unroll
  for (int fn = 0; fn < 4; ++fn) {
    int c = wave * 64 + fn * 16 + llo;
    const unsigned short* rowp;
    if (MODE == 0) {
      rowp = Wbase + (size_t)c * 128;
      bv[fn] = bias[c];
    } else {
      rowp = Wbase + (wave >= 2 ? 32768 : 0) + (size_t)(c & 127) * 256;
      bv[fn] = (wave >= 2) ? bias[c & 127] : 0.f;
    }
#pragma unroll
    for (int ks = 0; ks < 8; ++ks) {
      int koff = (MODE == 0) ? ((ks & 3) * 32 + lhi * 8 + ((ks >= 4) ? 32768 : 0))
                             : (ks * 32 + lhi * 8);
      bfrag[ks][fn] = *reinterpret_cast<const i32x4*>(rowp + koff);
    }
  }

  auto stage = [&](int buf, int row0) {
#pragma unroll
    for (int c = 0; c < 8; ++c) {
      int chunk = wave * 8 + c;
      int tb = chunk * 1024 + lane * 16;
      int r = tb >> 9;
      int cb = tb & 511;
      int cbs = cb ^ ((r & 7) << 4);     // involutive XOR swizzle (bits 4-6)
      int gr = min(row0 + r, NN - 1);
      const char* gsrc;
      if (MODE == 0) {
        const unsigned short* Asel = (cbs < 256) ? A1 : A2;
        gsrc = (const char*)(Asel + (size_t)gr * 128) + (cbs & 255);
      } else {
        gsrc = (const char*)(A1 + (size_t)gr * 256) + cbs;
      }
      __builtin_amdgcn_global_load_lds(
          (const __attribute__((address_space(1))) void*)gsrc,
          (__attribute__((address_space(3))) void*)((char*)As + buf * 32768 + chunk * 1024),
          16, 0, 0);
    }
  };

  const int npan = (NN + 63) >> 6;   // 1563
  int p = blockIdx.x;
  stage(0, p * 64);
  int cur = 0;

#pragma unroll 1
  for (; p < npan; p += gridDim.x) {
    int pn = p + gridDim.x;
    if (pn < npan) stage(cur ^ 1, pn * 64);
    // counted wait: in-order retirement => <=8 outstanding means current buffer's
    // 8 loads (issued before the 8 just staged) have landed. Never drains to 0.
    asm volatile("s_waitcnt vmcnt(8)" ::: "memory");
    __builtin_amdgcn_s_barrier();

    const int row0 = p * 64;
    f32x4 acc[4][4];
#pragma unroll
    for (int fm = 0; fm < 4; ++fm)
#pragma unroll
      for (int fn = 0; fn < 4; ++fn) acc[fm][fn] = (f32x4)0.f;

#pragma unroll
    for (int ks = 0; ks < 8; ++ks) {
      i32x4 a[4];
#pragma unroll
      for (int fm = 0; fm < 4; ++fm) {
        int r = fm * 16 + llo;
        int cb = (ks * 64 + lhi * 16) ^ ((r & 7) << 4);
        a[fm] = *reinterpret_cast<const i32x4*>((const char*)As + cur * 32768 + r * 512 + cb);
      }
#pragma unroll
      for (int fm = 0; fm < 4; ++fm)
#pragma unroll
        for (int fn = 0; fn < 4; ++fn)
          asm("v_mfma_f32_16x16x32_bf16 %0, %1, %2, %0"
              : "+v"(acc[fm][fn]) : "v"(a[fm]), "v"(bfrag[ks][fn]));
    }

    asm volatile("s_nop 7\n\ts_nop 7");   // MFMA -> VALU read hazard guard

#pragma unroll
    for (int fm = 0; fm < 4; ++fm) {
#pragma unroll
      for (int fn = 0; fn < 4; ++fn) {
        int col = wave * 64 + fn * 16 + llo;
#pragma unroll
        for (int j = 0; j < 4; ++j) {
          int row = row0 + fm * 16 + lhi * 4 + j;
          if (row < NN) {
            float v = acc[fm][fn][j] + bv[fn];
            if (MODE == 0) {
              v = fmaxf(v, 0.f);
              outb[(size_t)row * 256 + col] = f2bf(v);
            } else if (wave < 2) {
              outb[(size_t)row * 128 + col] = f2bf(v);
            } else {
              outb2[(size_t)row * 128 + (col - 128)] = f2bf(v);
            }
          }
        }
      }
    }
    __builtin_amdgcn_s_barrier();  // all waves done reading As[cur] before restage
    cur ^= 1;
  }
}

extern "C" void kernel_launch(void* const* d_in, const int* in_sizes, int n_in,
                              void* d_out, int out_size, void* d_ws, size_t ws_size,
                              hipStream_t stream) {
  const float* x   = (const float*)d_in[0];
  const int*   ei  = (const int*)d_in[1];
  const float* W1l = (const float*)d_in[2];
  const float* b1  = (const float*)d_in[3];
  const float* W1r = (const float*)d_in[4];
  const float* W2l = (const float*)d_in[5];
  const float* b2  = (const float*)d_in[6];
  const float* W2r = (const float*)d_in[7];
  float* out = (float*)d_out;

  char* ws = (char*)d_ws;
  float*          inv    = (float*)(ws);
  int*            degt   = (int*)(ws + 0x80000);
  int*            offs   = (int*)(ws + 0x100000);   // partial (scan1)
  int*            offs2  = (int*)(ws + 0x180000);   // finalized
  int*            bsum   = (int*)(ws + 0x200000);
  unsigned short* Wb     = (unsigned short*)(ws + 0x280000);  // 4 x 32768 bf16, packed
  int*            eidx   = (int*)(ws + 0x400000);
  unsigned short* xb     = (unsigned short*)(ws + 0x800000);   // [NN,128] bf16
  unsigned short* m1b    = (unsigned short*)(ws + 0x2200000);  // [NN,128] bf16; selfb in layer 2
  unsigned short* hb     = (unsigned short*)(ws + 0x3C00000);  // [NN,256] bf16
  unsigned short* hWb    = (unsigned short*)(ws + 0x6E00000);  // [NN,128] bf16
  int*            rord   = (int*)(ws + 0x8600000);             // [NE] int, packed (ord<<3)|c
  int*            deg8   = (int*)(ws + 0x8A00000);             // [8][NN] int replicas
  int*            xcdoff = (int*)(ws + 0x8E00000);             // [8][NN] int bases
  unsigned short* selfb  = m1b;   // m1b dead after layer-1 GEMM

  const int* src = ei;
  const int* dst = ei + NE;
  const int NB = (NN + 1023) / 1024;  // 98

  // ---- fused prologue: XCD-local degree replicas overlapped with x/W casts ----
  hipMemsetAsync(deg8, 0, 8 * NN * sizeof(int), stream);
  prep_k<<<NBDEG + NBX + NBW, 256, 0, stream>>>(x, W1l, W1r, W2l, W2r, dst,
                                                xb, Wb, deg8, rord);
  scan1_k<<<NB, 256, 0, stream>>>(deg8, degt, offs, bsum, inv);
  scan2_k<<<1, 256, 0, stream>>>(bsum, NB);
  fin_k<<<NBFIN, 256, 0, stream>>>(offs, bsum, deg8, offs2, xcdoff);
  fill_k<<<(NE + 255) / 256, 256, 0, stream>>>(src, dst, xcdoff, rord, eidx);

  // ---- layer 1: m1 = gather(x); h = relu([m1|x] @ [W1l|W1r]^T + b1) ----
  gather_k<0><<<2048, 256, 0, stream>>>(xb, offs2, degt, inv, eidx, nullptr, m1b, nullptr);
  mgemm_k<0><<<512, 256, 0, stream>>>(m1b, xb, Wb, b1, hb, nullptr);

  // ---- layer 2 (transform-first): hWb = bf16(h@W2l), selfb = bf16(h@W2r + b2);
  //      out = selfb + inv * gather(hWb) ----
  mgemm_k<1><<<512, 256, 0, stream>>>(hb, nullptr, Wb + 65536, b2, hWb, selfb);
  gather_k<2><<<2048, 256, 0, stream>>>(hWb, offs2, degt, inv, eidx, selfb, nullptr, out);
}

// Round 14
// 212.232 us; speedup vs baseline: 1.0827x; 1.0827x over previous
//
#include <hip/hip_runtime.h>

#define NN 100000
#define NE 800000

typedef __attribute__((ext_vector_type(4))) float f32x4;
typedef __attribute__((ext_vector_type(4))) int   i32x4;
typedef __attribute__((ext_vector_type(8))) unsigned short u16x8;

__device__ __forceinline__ unsigned short f2bf(float f) {
  unsigned u = __float_as_uint(f);
  return (unsigned short)((u + 0x7FFFu + ((u >> 16) & 1u)) >> 16);
}
__device__ __forceinline__ float bf2f(unsigned short b) {
  return __uint_as_float(((unsigned)b) << 16);
}

// ---------------- fused prologue: degree atomics INTERLEAVED with casts ----------------
// Atomic blocks are spread through the grid (bid%5==0) so every CU runs the
// atomic-latency waves concurrently with streaming cast waves (r11 ran all
// atomic blocks first -> phases serialized; casts never hid).
#define NBDEG 3125                   // 800000 / 256
#define NXV   (NN * 128 / 4)         // 3200000 float4 chunks
#define NBX   12500                  // NXV / 256
#define NBW   512                    // 131072 / 256
#define NBPREP (NBDEG + NBX + NBW)   // 16137
__global__ __launch_bounds__(256) void prep_k(
    const float* __restrict__ x,
    const float* __restrict__ Wa, const float* __restrict__ Wbm,
    const float* __restrict__ Wc, const float* __restrict__ Wd,
    const int* __restrict__ dst,
    unsigned short* __restrict__ xb, unsigned short* __restrict__ Wbo,
    int* __restrict__ deg, int* __restrict__ rord) {
  int bid = blockIdx.x, t = threadIdx.x;
  bool is_deg = (bid % 5 == 0) && (bid < 15625);
  if (is_deg) {
    int e = (bid / 5) * 256 + t;
    int o = atomicAdd(&deg[dst[e]], 1);
    __builtin_nontemporal_store(o, &rord[e]);
  } else {
    int cidx = bid - min(NBDEG, bid / 5 + 1);
    if (cidx < NBX) {
      int i = cidx * 256 + t;
      f32x4 v = __builtin_nontemporal_load(
          reinterpret_cast<const f32x4*>(x + (size_t)i * 4));
      ushort4 o;
      o.x = f2bf(v[0]); o.y = f2bf(v[1]); o.z = f2bf(v[2]); o.w = f2bf(v[3]);
      *reinterpret_cast<ushort4*>(xb + (size_t)i * 4) = o;
    } else {
      int k = (cidx - NBX) * 256 + t;
      int seg = k >> 15, off = k & 32767;
      const float* s = (seg < 2) ? (seg == 0 ? Wa : Wbm) : (seg == 2 ? Wc : Wd);
      Wbo[k] = f2bf(s[off]);
    }
  }
}

// ---------------- CSR scan (block-level partial) ----------------
__global__ __launch_bounds__(256) void scan1_k(const int* __restrict__ deg,
    int* __restrict__ offs, int* __restrict__ bsum, float* __restrict__ inv) {
  __shared__ int s[256];
  int t = threadIdx.x;
  int base = blockIdx.x * 1024 + t * 4;
  int v[4], tsum = 0;
#pragma unroll
  for (int k = 0; k < 4; ++k) {
    int i = base + k;
    v[k] = (i < NN) ? deg[i] : 0;
    tsum += v[k];
    if (i < NN) inv[i] = 1.0f / fmaxf((float)v[k], 1.0f);
  }
  s[t] = tsum; __syncthreads();
  int val = tsum;
#pragma unroll
  for (int off = 1; off < 256; off <<= 1) {
    int x = (t >= off) ? s[t - off] : 0;
    __syncthreads();
    val += x; s[t] = val;
    __syncthreads();
  }
  int excl = val - tsum;
  if (t == 255) bsum[blockIdx.x] = val;
  int run = excl;
#pragma unroll
  for (int k = 0; k < 4; ++k) { int i = base + k; if (i < NN) offs[i] = run; run += v[k]; }
}

// ---------------- fused: in-block bsum prefix + finalize offs2 + fill ----------------
// Every block computes the exclusive prefix of the 98 block sums in LDS (replaces
// scan2's separate launch), then either finalizes offs2 or fills edges.
// eidx store is a NORMAL store (not nt): same-dst slots are contiguous; L2 line
// coalescing cuts the 16x write amplification the nt dword scatter caused.
#define NBFIN 98                     // ceil(NN/1024)
__global__ __launch_bounds__(256) void finfill_k(
    const int* __restrict__ offs, const int* __restrict__ bsum,
    int* __restrict__ offs2,
    const int* __restrict__ src, const int* __restrict__ dst,
    const int* __restrict__ rord, int* __restrict__ eidx) {
  __shared__ int s[256];
  __shared__ int ex[NBFIN];
  int bid = blockIdx.x, t = threadIdx.x;
  int v = (t < NBFIN) ? bsum[t] : 0;
  s[t] = v; __syncthreads();
  int val = v;
#pragma unroll
  for (int off = 1; off < 256; off <<= 1) {
    int x = (t >= off) ? s[t - off] : 0;
    __syncthreads();
    val += x; s[t] = val;
    __syncthreads();
  }
  if (t < NBFIN) ex[t] = val - v;   // exclusive prefix
  __syncthreads();

  if (bid < NBFIN) {
    int base = bid * 1024 + t * 4;
    int add = ex[bid];
#pragma unroll
    for (int k = 0; k < 4; ++k) {
      int i = base + k;
      if (i < NN) offs2[i] = offs[i] + add;
    }
  } else {
    int e = (bid - NBFIN) * 256 + t;
    if (e < NE) {
      int d = dst[e];
      int p = offs[d] + ex[d >> 10] + rord[e];
      eidx[p] = src[e];
    }
  }
}

// ---------------- gather (bf16 table, fp32 accum, deep ILP, grid-stride) ----------------
// 16 lanes/node, 16B (8 bf16) per lane; unroll x8 + x4 + scalar tails.
// GMODE 0: outb(bf16)[node] = bf16(inv*sum(feat[nbr]))
// GMODE 2: outf(f32)[node]  = bf2f(selfb[node]) + inv*sum(feat[nbr])  (nt store)
template<int GMODE>
__global__ __launch_bounds__(256) void gather_k(const unsigned short* __restrict__ feat,
    const int* __restrict__ offs, const int* __restrict__ deg,
    const float* __restrict__ inv, const int* __restrict__ eidx,
    const unsigned short* __restrict__ selfb,
    unsigned short* __restrict__ outb, float* __restrict__ outf) {
  const int l = threadIdx.x & 15;
  for (int nb = blockIdx.x * 16; nb < NN; nb += gridDim.x * 16) {
    int node = nb + (threadIdx.x >> 4);
    if (node >= NN) continue;
    int st = offs[node], n = deg[node];
    float a[8];
#pragma unroll
    for (int k = 0; k < 8; ++k) a[k] = 0.f;

    int j = 0;
    for (; j + 8 <= n; j += 8) {
      int si[8];
#pragma unroll
      for (int q = 0; q < 8; ++q) si[q] = eidx[st + j + q];
      u16x8 r[8];
#pragma unroll
      for (int q = 0; q < 8; ++q)
        r[q] = *reinterpret_cast<const u16x8*>(feat + (size_t)si[q] * 128 + l * 8);
#pragma unroll
      for (int q = 0; q < 8; ++q)
#pragma unroll
        for (int k = 0; k < 8; ++k) a[k] += bf2f(r[q][k]);
    }
    for (; j + 4 <= n; j += 4) {
      int si[4];
#pragma unroll
      for (int q = 0; q < 4; ++q) si[q] = eidx[st + j + q];
      u16x8 r[4];
#pragma unroll
      for (int q = 0; q < 4; ++q)
        r[q] = *reinterpret_cast<const u16x8*>(feat + (size_t)si[q] * 128 + l * 8);
#pragma unroll
      for (int q = 0; q < 4; ++q)
#pragma unroll
        for (int k = 0; k < 8; ++k) a[k] += bf2f(r[q][k]);
    }
    for (; j < n; ++j) {
      int s = eidx[st + j];
      u16x8 r = *reinterpret_cast<const u16x8*>(feat + (size_t)s * 128 + l * 8);
#pragma unroll
      for (int k = 0; k < 8; ++k) a[k] += bf2f(r[k]);
    }

    float sc = inv[node];
    if (GMODE == 2) {
      u16x8 sb = *reinterpret_cast<const u16x8*>(selfb + (size_t)node * 128 + l * 8);
      f32x4 o0, o1;
      o0[0] = bf2f(sb[0]) + sc * a[0]; o0[1] = bf2f(sb[1]) + sc * a[1];
      o0[2] = bf2f(sb[2]) + sc * a[2]; o0[3] = bf2f(sb[3]) + sc * a[3];
      o1[0] = bf2f(sb[4]) + sc * a[4]; o1[1] = bf2f(sb[5]) + sc * a[5];
      o1[2] = bf2f(sb[6]) + sc * a[6]; o1[3] = bf2f(sb[7]) + sc * a[7];
      float* po = outf + (size_t)node * 128 + l * 8;
      __builtin_nontemporal_store(o0, reinterpret_cast<f32x4*>(po));
      __builtin_nontemporal_store(o1, reinterpret_cast<f32x4*>(po + 4));
    } else {
      u16x8 o;
#pragma unroll
      for (int k = 0; k < 8; ++k) o[k] = f2bf(sc * a[k]);
      *reinterpret_cast<u16x8*>(outb + (size_t)node * 128 + l * 8) = o;
    }
  }
}

// ---------------- persistent bf16 MFMA GEMM (64 rows x 256 cols / panel) --------
// Grid = 512 persistent blocks (2/CU, 64KB LDS dbuf). B fragments preloaded once.
// Panel loop: stage(next)->vmcnt(8) counted->raw barrier->MFMA+stores->raw barrier.
// MODE 0 (layer 1): A=[A1|A2] k-concat; B k-concat; out = bf16 relu(C+bias) -> outb [NN,256].
// MODE 1 (layer 2): A=A1 [M,256]; B out-concat; waves 0-1 -> outb = bf16(h@W2l) [NN,128];
//   waves 2-3 -> outb2 = bf16(h@W2r + bias) [NN,128].
template<int MODE>
__global__ __launch_bounds__(256, 2) void mgemm_k(
    const unsigned short* __restrict__ A1, const unsigned short* __restrict__ A2,
    const unsigned short* __restrict__ Wbase, const float* __restrict__ bias,
    unsigned short* __restrict__ outb, unsigned short* __restrict__ outb2) {
  __shared__ unsigned short As[2][64 * 256];   // 2 x 32 KB, row stride 512 B
  const int t = threadIdx.x;
  const int wave = t >> 6, lane = t & 63;
  const int lhi = lane >> 4, llo = lane & 15;

  // ---- B fragments + bias, loaded once (weights are L2-resident) ----
  i32x4 bfrag[8][4];
  float bv[4];
#pragma unroll
  for (int fn = 0; fn < 4; ++fn) {
    int c = wave * 64 + fn * 16 + llo;
    const unsigned short* rowp;
    if (MODE == 0) {
      rowp = Wbase + (size_t)c * 128;
      bv[fn] = bias[c];
    } else {
      rowp = Wbase + (wave >= 2 ? 32768 : 0) + (size_t)(c & 127) * 256;
      bv[fn] = (wave >= 2) ? bias[c & 127] : 0.f;
    }
#pragma unroll
    for (int ks = 0; ks < 8; ++ks) {
      int koff = (MODE == 0) ? ((ks & 3) * 32 + lhi * 8 + ((ks >= 4) ? 32768 : 0))
                             : (ks * 32 + lhi * 8);
      bfrag[ks][fn] = *reinterpret_cast<const i32x4*>(rowp + koff);
    }
  }

  auto stage = [&](int buf, int row0) {
#pragma unroll
    for (int c = 0; c < 8; ++c) {
      int chunk = wave * 8 + c;
      int tb = chunk * 1024 + lane * 16;
      int r = tb >> 9;
      int cb = tb & 511;
      int cbs = cb ^ ((r & 7) << 4);     // involutive XOR swizzle (bits 4-6)
      int gr = min(row0 + r, NN - 1);
      const char* gsrc;
      if (MODE == 0) {
        const unsigned short* Asel = (cbs < 256) ? A1 : A2;
        gsrc = (const char*)(Asel + (size_t)gr * 128) + (cbs & 255);
      } else {
        gsrc = (const char*)(A1 + (size_t)gr * 256) + cbs;
      }
      __builtin_amdgcn_global_load_lds(
          (const __attribute__((address_space(1))) void*)gsrc,
          (__attribute__((address_space(3))) void*)((char*)As + buf * 32768 + chunk * 1024),
          16, 0, 0);
    }
  };

  const int npan = (NN + 63) >> 6;   // 1563
  int p = blockIdx.x;
  stage(0, p * 64);
  int cur = 0;

#pragma unroll 1
  for (; p < npan; p += gridDim.x) {
    int pn = p + gridDim.x;
    if (pn < npan) stage(cur ^ 1, pn * 64);
    // counted wait: in-order retirement => <=8 outstanding means current buffer's
    // 8 loads (issued before the 8 just staged) have landed. Never drains to 0.
    asm volatile("s_waitcnt vmcnt(8)" ::: "memory");
    __builtin_amdgcn_s_barrier();

    const int row0 = p * 64;
    f32x4 acc[4][4];
#pragma unroll
    for (int fm = 0; fm < 4; ++fm)
#pragma unroll
      for (int fn = 0; fn < 4; ++fn) acc[fm][fn] = (f32x4)0.f;

#pragma unroll
    for (int ks = 0; ks < 8; ++ks) {
      i32x4 a[4];
#pragma unroll
      for (int fm = 0; fm < 4; ++fm) {
        int r = fm * 16 + llo;
        int cb = (ks * 64 + lhi * 16) ^ ((r & 7) << 4);
        a[fm] = *reinterpret_cast<const i32x4*>((const char*)As + cur * 32768 + r * 512 + cb);
      }
#pragma unroll
      for (int fm = 0; fm < 4; ++fm)
#pragma unroll
        for (int fn = 0; fn < 4; ++fn)
          asm("v_mfma_f32_16x16x32_bf16 %0, %1, %2, %0"
              : "+v"(acc[fm][fn]) : "v"(a[fm]), "v"(bfrag[ks][fn]));
    }

    asm volatile("s_nop 7\n\ts_nop 7");   // MFMA -> VALU read hazard guard

#pragma unroll
    for (int fm = 0; fm < 4; ++fm) {
#pragma unroll
      for (int fn = 0; fn < 4; ++fn) {
        int col = wave * 64 + fn * 16 + llo;
#pragma unroll
        for (int j = 0; j < 4; ++j) {
          int row = row0 + fm * 16 + lhi * 4 + j;
          if (row < NN) {
            float v = acc[fm][fn][j] + bv[fn];
            if (MODE == 0) {
              v = fmaxf(v, 0.f);
              outb[(size_t)row * 256 + col] = f2bf(v);
            } else if (wave < 2) {
              outb[(size_t)row * 128 + col] = f2bf(v);
            } else {
              outb2[(size_t)row * 128 + (col - 128)] = f2bf(v);
            }
          }
        }
      }
    }
    __builtin_amdgcn_s_barrier();  // all waves done reading As[cur] before restage
    cur ^= 1;
  }
}

extern "C" void kernel_launch(void* const* d_in, const int* in_sizes, int n_in,
                              void* d_out, int out_size, void* d_ws, size_t ws_size,
                              hipStream_t stream) {
  const float* x   = (const float*)d_in[0];
  const int*   ei  = (const int*)d_in[1];
  const float* W1l = (const float*)d_in[2];
  const float* b1  = (const float*)d_in[3];
  const float* W1r = (const float*)d_in[4];
  const float* W2l = (const float*)d_in[5];
  const float* b2  = (const float*)d_in[6];
  const float* W2r = (const float*)d_in[7];
  float* out = (float*)d_out;

  char* ws = (char*)d_ws;
  float*          inv    = (float*)(ws);
  int*            deg    = (int*)(ws + 0x80000);
  int*            offs   = (int*)(ws + 0x100000);   // partial (scan1)
  int*            offs2  = (int*)(ws + 0x180000);   // finalized
  int*            bsum   = (int*)(ws + 0x200000);
  unsigned short* Wb     = (unsigned short*)(ws + 0x280000);  // 4 x 32768 bf16, packed
  int*            eidx   = (int*)(ws + 0x400000);
  unsigned short* xb     = (unsigned short*)(ws + 0x800000);   // [NN,128] bf16
  unsigned short* m1b    = (unsigned short*)(ws + 0x2200000);  // [NN,128] bf16; selfb in layer 2
  unsigned short* hb     = (unsigned short*)(ws + 0x3C00000);  // [NN,256] bf16
  unsigned short* hWb    = (unsigned short*)(ws + 0x6E00000);  // [NN,128] bf16
  int*            rord   = (int*)(ws + 0x8600000);             // [NE] int
  unsigned short* selfb  = m1b;   // m1b dead after layer-1 GEMM

  const int* src = ei;
  const int* dst = ei + NE;
  const int NB = (NN + 1023) / 1024;  // 98

  // ---- fused prologue: degree atomics interleaved with x/W casts ----
  hipMemsetAsync(deg, 0, NN * sizeof(int), stream);
  prep_k<<<NBPREP, 256, 0, stream>>>(x, W1l, W1r, W2l, W2r, dst, xb, Wb, deg, rord);
  scan1_k<<<NB, 256, 0, stream>>>(deg, offs, bsum, inv);
  // in-block bsum prefix + finalize offs2 + atomic-free fill (normal stores)
  finfill_k<<<NBFIN + (NE + 255) / 256, 256, 0, stream>>>(offs, bsum, offs2,
                                                          src, dst, rord, eidx);

  // ---- layer 1: m1 = gather(x); h = relu([m1|x] @ [W1l|W1r]^T + b1) ----
  gather_k<0><<<2048, 256, 0, stream>>>(xb, offs2, deg, inv, eidx, nullptr, m1b, nullptr);
  mgemm_k<0><<<512, 256, 0, stream>>>(m1b, xb, Wb, b1, hb, nullptr);

  // ---- layer 2 (transform-first): hWb = bf16(h@W2l), selfb = bf16(h@W2r + b2);
  //      out = selfb + inv * gather(hWb) ----
  mgemm_k<1><<<512, 256, 0, stream>>>(hb, nullptr, Wb + 65536, b2, hWb, selfb);
  gather_k<2><<<2048, 256, 0, stream>>>(hWb, offs2, deg, inv, eidx, selfb, nullptr, out);
}